// Round 7
// baseline (1778.549 us; speedup 1.0000x reference)
//
#include <hip/hip_runtime.h>
#include <hip/hip_fp16.h>

// ---------------------------------------------------------------------------
// GNN policy: 2x GCNConv (N=100k, H=64) + per-edge MLP (132->64->1).
// R7: CSR build (count/scan/fill, ~230us, 64B/edge write-amp) replaced by a
// 64-node bucket partition (LDS histogram + atomic range reservation ->
// frontier-coalesced writes) and bucket-level aggregation into LDS fp32
// tiles via ds_add_f32. dis from per-bucket LDS degree histogram. Layer-1
// agg fused with the W1 transform. gemm64b/pq/edgefin verbatim from R6.
// ---------------------------------------------------------------------------

#define HDIM 64
#define NBK 2048          // padded bucket count (nbuck = ceil(N/64) = 1563)

// ---------------- bucket partition ----------------

__global__ void __launch_bounds__(256) hist_k(const int* __restrict__ dst,
                                              int* __restrict__ bucketCnt,
                                              int E, int CH) {
    __shared__ int hist[NBK];
    int t = threadIdx.x;
    for (int b = t; b < NBK; b += 256) hist[b] = 0;
    __syncthreads();
    int rs = blockIdx.x * CH, re = min(E, rs + CH);
    for (int e = rs + t; e < re; e += 256) atomicAdd(&hist[dst[e] >> 6], 1);
    __syncthreads();
    for (int b = t; b < NBK; b += 256) {
        int h = hist[b];
        if (h) atomicAdd(&bucketCnt[b], h);
    }
}

// exclusive scan of 2048 bucket counts; writes base (2049) and cur (=base)
__global__ void bscan_k(const int* __restrict__ cnt, int* __restrict__ base,
                        int* __restrict__ cur, int E) {
    __shared__ int wtot[4];
    int t = threadIdx.x;
    int lane = t & 63, wid = t >> 6;
    int i0 = t * 8;
    int v[8]; int s = 0;
    #pragma unroll
    for (int j = 0; j < 8; j++) { v[j] = cnt[i0 + j]; s += v[j]; }
    int ws = s;
    #pragma unroll
    for (int d = 1; d < 64; d <<= 1) {
        int n = __shfl_up(ws, d, 64);
        if (lane >= d) ws += n;
    }
    if (lane == 63) wtot[wid] = ws;
    __syncthreads();
    int woff = 0;
    #pragma unroll
    for (int w = 0; w < 4; w++) if (w < wid) woff += wtot[w];
    int ex = woff + ws - s;
    #pragma unroll
    for (int j = 0; j < 8; j++) {
        base[i0 + j] = ex; cur[i0 + j] = ex;
        ex += v[j];
    }
    if (t == 255) base[NBK] = E;
}

// partition edges into bucket regions: per-block LDS hist -> atomic range
// reservation on bucketCur -> frontier writes (temporally coalesced).
__global__ void __launch_bounds__(256) part_k(const int* __restrict__ src,
                                              const int* __restrict__ dst,
                                              int* __restrict__ bucketCur,
                                              int2* __restrict__ pairs,
                                              int E, int CH) {
    __shared__ int hist[NBK];
    __shared__ int mybase[NBK];
    __shared__ int lcur[NBK];
    int t = threadIdx.x;
    int rs = blockIdx.x * CH, re = min(E, rs + CH);
    for (int b = t; b < NBK; b += 256) hist[b] = 0;
    __syncthreads();
    for (int e = rs + t; e < re; e += 256) atomicAdd(&hist[dst[e] >> 6], 1);
    __syncthreads();
    for (int b = t; b < NBK; b += 256) {
        int h = hist[b];
        mybase[b] = h ? atomicAdd(&bucketCur[b], h) : 0;
        lcur[b] = 0;
    }
    __syncthreads();
    for (int e = rs + t; e < re; e += 256) {
        int d = dst[e];
        int b = d >> 6;
        int o = atomicAdd(&lcur[b], 1);
        pairs[mybase[b] + o] = make_int2(src[e], d);
    }
}

// per-bucket degree histogram -> dis = rsqrt(deg+1)
__global__ void ddis_k(const int2* __restrict__ pairs, const int* __restrict__ base,
                       float* __restrict__ dis, int N) {
    __shared__ int cnt[64];
    int b = blockIdx.x, t = threadIdx.x;
    if (t < 64) cnt[t] = 0;
    __syncthreads();
    int rs = base[b], re = base[b + 1];
    for (int i = rs + t; i < re; i += 256) atomicAdd(&cnt[pairs[i].y & 63], 1);
    __syncthreads();
    int n = b * 64 + t;
    if (t < 64 && n < N) dis[n] = rsqrtf((float)(cnt[t] + 1));
}

// ---------------- layer 1: bucket-agg of x (4-dim) fused with W1 transform ---
// acc[i] = sum norm*x[src] ; h1 = relu((acc + dis_i^2*x[i]) @ W1 + b1) fp16
__global__ void __launch_bounds__(256) aggXh1_k(
    const int2* __restrict__ pairs, const int* __restrict__ base,
    const float* __restrict__ x, const float* __restrict__ dis,
    const float* __restrict__ W1, const float* __restrict__ b1,
    __half* __restrict__ h1, int N) {
    __shared__ float acc[64 * 4];
    int b = blockIdx.x, t = threadIdx.x;
    acc[t] = 0.f;
    __syncthreads();
    int rs = base[b], re = base[b + 1];
    for (int g4 = rs * 4 + t; g4 < re * 4; g4 += 256) {
        int e = g4 >> 2, f = g4 & 3;
        int2 p = pairs[e];
        float nrm = dis[p.x] * dis[p.y];
        atomicAdd(&acc[(p.y & 63) * 4 + f], x[(size_t)p.x * 4 + f] * nrm);
    }
    __syncthreads();
    for (int idx = t; idx < 64 * 64; idx += 256) {
        int nl = idx >> 6, f = idx & 63;
        int n = b * 64 + nl;
        if (n >= N) break;
        float di = dis[n], d2 = di * di;
        float a0 = acc[nl * 4 + 0] + d2 * x[(size_t)n * 4 + 0];
        float a1 = acc[nl * 4 + 1] + d2 * x[(size_t)n * 4 + 1];
        float a2 = acc[nl * 4 + 2] + d2 * x[(size_t)n * 4 + 2];
        float a3 = acc[nl * 4 + 3] + d2 * x[(size_t)n * 4 + 3];
        float hv = b1[f];
        hv = fmaf(a0, W1[f], hv);
        hv = fmaf(a1, W1[64 + f], hv);
        hv = fmaf(a2, W1[128 + f], hv);
        hv = fmaf(a3, W1[192 + f], hv);
        h1[(size_t)n * 64 + f] = __float2half(fmaxf(hv, 0.f));
    }
}

// ---------------- layer 2: bucket-agg of fp16 h1 into 64x64 LDS tile ---------
// g[i] = sum norm*h1[src] + dis_i^2*h1[i]  (fp32 LDS accum, fp16 out)
__global__ void __launch_bounds__(256) agg2b_k(
    const int2* __restrict__ pairs, const int* __restrict__ base,
    const __half* __restrict__ h1, const float* __restrict__ dis,
    __half* __restrict__ g, int N) {
    __shared__ float acc[64 * 64];   // 16 KB
    int b = blockIdx.x, t = threadIdx.x;
    for (int i = t; i < 64 * 64; i += 256) acc[i] = 0.f;
    __syncthreads();
    int rs = base[b], re = base[b + 1];
    int w = t >> 6, lane = t & 63, side = lane >> 5, lh = lane & 31;
    for (int e0 = rs + w * 4; e0 < re; e0 += 16) {
        int e1 = e0 + side * 2, e2 = e1 + 1;
        bool k1 = e1 < re, k2 = e2 < re;
        int2 p1, p2;
        if (k1) p1 = pairs[e1];
        if (k2) p2 = pairs[e2];
        float n1 = 0.f, n2 = 0.f;
        float2 v1 = {0.f, 0.f}, v2 = {0.f, 0.f};
        if (k1) {
            n1 = dis[p1.x] * dis[p1.y];
            v1 = __half22float2(*(const __half2*)(h1 + (size_t)p1.x * 64 + lh * 2));
        }
        if (k2) {
            n2 = dis[p2.x] * dis[p2.y];
            v2 = __half22float2(*(const __half2*)(h1 + (size_t)p2.x * 64 + lh * 2));
        }
        if (k1) {
            int dl = (p1.y & 63) * 64 + lh * 2;
            atomicAdd(&acc[dl], v1.x * n1);
            atomicAdd(&acc[dl + 1], v1.y * n1);
        }
        if (k2) {
            int dl = (p2.y & 63) * 64 + lh * 2;
            atomicAdd(&acc[dl], v2.x * n2);
            atomicAdd(&acc[dl + 1], v2.y * n2);
        }
    }
    __syncthreads();
    for (int idx = t; idx < 64 * 64; idx += 256) {
        int nl = idx >> 6, f = idx & 63;
        int n = b * 64 + nl;
        if (n >= N) break;
        float di = dis[n];
        float v = acc[idx] + di * di * __half2float(h1[(size_t)n * 64 + f]);
        g[(size_t)n * 64 + f] = __float2half(v);
    }
}

// ---------------- h2 = relu(g @ W2 + b2) ----------------
__global__ void gemm64b_k(const __half* __restrict__ gin, const float* __restrict__ W2,
                          const float* __restrict__ b2, float* __restrict__ h2, int N) {
    __shared__ float w[64 * 64];
    int t = threadIdx.x;
    for (int j = t; j < 64 * 64; j += 256) w[j] = W2[j];
    __syncthreads();
    int gid = blockIdx.x * 256 + t;
    if (gid >= N * HDIM) return;
    int i = gid >> 6, f = gid & 63;
    const __half2* hr = (const __half2*)(gin + (size_t)i * HDIM);
    float acc = 0.f;
    #pragma unroll 8
    for (int k = 0; k < 32; k++) {
        float2 hv = __half22float2(hr[k]);
        acc = fmaf(hv.x, w[(2 * k) * 64 + f], acc);
        acc = fmaf(hv.y, w[(2 * k + 1) * 64 + f], acc);
    }
    h2[gid] = fmaxf(acc + b2[f], 0.f);
}

// P = h2@Wm1[0:64]+bm1, Q = h2@Wm1[64:128]  (fp16)
__global__ void pq_k(const float* __restrict__ h, const float* __restrict__ Wm1,
                     const float* __restrict__ bm1,
                     __half* __restrict__ Ph, __half* __restrict__ Qh, int N) {
    __shared__ float w[128 * 64];
    int t = threadIdx.x;
    for (int j = t; j < 128 * 64; j += 256) w[j] = Wm1[j];
    __syncthreads();
    int gid = blockIdx.x * 256 + t;
    if (gid >= N * HDIM) return;
    int i = gid >> 6, f = gid & 63;
    const float* hr = h + (size_t)i * HDIM;
    float a = bm1[f], b = 0.f;
    #pragma unroll 8
    for (int k = 0; k < 64; k++) {
        float hv = hr[k];
        a = fmaf(hv, w[k * 64 + f], a);
        b = fmaf(hv, w[(64 + k) * 64 + f], b);
    }
    Ph[gid] = __float2half(a);
    Qh[gid] = __float2half(b);
}

// ---------------- edge finalize (verbatim R6) ----------------
__device__ __forceinline__ float mlp8(uint4 pv, uint4 qv, float4 eav,
                                      const float wer[4][8], const float w2r[8]) {
    float p = 0.f;
    #pragma unroll
    for (int w = 0; w < 4; w++) {
        unsigned pu = (&pv.x)[w], qu = (&qv.x)[w];
        float2 pf = __half22float2(__builtin_bit_cast(__half2, pu));
        float2 qf = __half22float2(__builtin_bit_cast(__half2, qu));
        int j0 = 2 * w, j1 = 2 * w + 1;
        float z0 = pf.x + qf.x;
        z0 = fmaf(eav.x, wer[0][j0], z0); z0 = fmaf(eav.y, wer[1][j0], z0);
        z0 = fmaf(eav.z, wer[2][j0], z0); z0 = fmaf(eav.w, wer[3][j0], z0);
        float z1 = pf.y + qf.y;
        z1 = fmaf(eav.x, wer[0][j1], z1); z1 = fmaf(eav.y, wer[1][j1], z1);
        z1 = fmaf(eav.z, wer[2][j1], z1); z1 = fmaf(eav.w, wer[3][j1], z1);
        p = fmaf(fmaxf(z0, 0.f), w2r[j0], p);
        p = fmaf(fmaxf(z1, 0.f), w2r[j1], p);
    }
    return p;
}

__global__ void __launch_bounds__(256) edgefin_k(
    const int* __restrict__ src, const int* __restrict__ dst,
    const float* __restrict__ ea,
    const __half* __restrict__ Ph, const __half* __restrict__ Qh,
    const float* __restrict__ Wm1, const float* __restrict__ Wm2,
    const float* __restrict__ bm2, float* __restrict__ out, int E) {
    int q = threadIdx.x & 7;
    int fb = q * 8;
    float w2r[8];
    float wer[4][8];
    *(float4*)&w2r[0] = *(const float4*)(Wm2 + fb);
    *(float4*)&w2r[4] = *(const float4*)(Wm2 + fb + 4);
    #pragma unroll
    for (int r = 0; r < 4; r++) {
        *(float4*)&wer[r][0] = *(const float4*)(Wm1 + (128 + r) * 64 + fb);
        *(float4*)&wer[r][4] = *(const float4*)(Wm1 + (128 + r) * 64 + fb + 4);
    }
    float b2v = bm2[0];

    int base = blockIdx.x * 64 + (threadIdx.x >> 3);
    int gstride = gridDim.x * 64;
    for (int e1 = base; e1 < E; e1 += gstride) {
        int e2 = e1 + 32; int e2c = (e2 < E) ? e2 : (E - 1);
        int s1 = src[e1], d1 = dst[e1];
        int s2 = src[e2c], d2 = dst[e2c];
        uint4 pv1 = *(const uint4*)((const unsigned short*)Ph + (size_t)s1 * HDIM + fb);
        uint4 qv1 = *(const uint4*)((const unsigned short*)Qh + (size_t)d1 * HDIM + fb);
        uint4 pv2 = *(const uint4*)((const unsigned short*)Ph + (size_t)s2 * HDIM + fb);
        uint4 qv2 = *(const uint4*)((const unsigned short*)Qh + (size_t)d2 * HDIM + fb);
        float4 ea1 = *(const float4*)(ea + (size_t)e1 * 4);
        float4 ea2 = *(const float4*)(ea + (size_t)e2c * 4);
        float p1 = mlp8(pv1, qv1, ea1, wer, w2r);
        float p2 = mlp8(pv2, qv2, ea2, wer, w2r);
        p1 += __shfl_xor(p1, 1, 64); p1 += __shfl_xor(p1, 2, 64); p1 += __shfl_xor(p1, 4, 64);
        p2 += __shfl_xor(p2, 1, 64); p2 += __shfl_xor(p2, 2, 64); p2 += __shfl_xor(p2, 4, 64);
        if (q == 0) {
            out[e1] = p1 + b2v;
            if (e2 < E) out[e2] = p2 + b2v;
        }
    }
}

extern "C" void kernel_launch(void* const* d_in, const int* in_sizes, int n_in,
                              void* d_out, int out_size, void* d_ws, size_t ws_size,
                              hipStream_t stream) {
    const float* x   = (const float*)d_in[0];
    const int*   ei  = (const int*)d_in[1];
    const float* ea  = (const float*)d_in[2];
    const float* W1  = (const float*)d_in[3];
    const float* b1  = (const float*)d_in[4];
    const float* W2  = (const float*)d_in[5];
    const float* b2  = (const float*)d_in[6];
    const float* Wm1 = (const float*)d_in[7];
    const float* bm1 = (const float*)d_in[8];
    const float* Wm2 = (const float*)d_in[9];
    const float* bm2 = (const float*)d_in[10];
    float* out = (float*)d_out;

    int N = in_sizes[0] / 4;    // 100000
    int E = in_sizes[1] / 2;    // 3200000
    const int* src = ei;
    const int* dst = ei + E;
    int nbuck = (N + 63) >> 6;  // 1563

    char* wp = (char*)d_ws;
    auto carve = [&](size_t bytes) -> void* {
        void* p = (void*)wp;
        wp += (bytes + 255) & ~(size_t)255;
        return p;
    };
    int*   bucketCnt  = (int*)carve(NBK * 4);
    int*   bucketBase = (int*)carve((NBK + 1) * 4);
    int*   bucketCur  = (int*)carve(NBK * 4);
    float* dis        = (float*)carve((size_t)N * 4);
    int2*  pairs      = (int2*)carve((size_t)E * 8);
    float*  S1 = (float*)carve((size_t)N * HDIM * 4);    // h2
    __half* S2 = (__half*)carve((size_t)N * HDIM * 2);   // h1 -> Qh
    __half* S3 = (__half*)carve((size_t)N * HDIM * 2);   // g  -> Ph
    __half* h1 = S2;
    __half* g  = S3;
    float*  h2 = S1;
    __half* Ph = S3;
    __half* Qh = S2;

    hipMemsetAsync(bucketCnt, 0, NBK * 4, stream);

    int CH = (E + 511) / 512;   // 6250 edges per partition block

    hist_k<<<512, 256, 0, stream>>>(dst, bucketCnt, E, CH);
    bscan_k<<<1, 256, 0, stream>>>(bucketCnt, bucketBase, bucketCur, E);
    part_k<<<512, 256, 0, stream>>>(src, dst, bucketCur, pairs, E, CH);
    ddis_k<<<nbuck, 256, 0, stream>>>(pairs, bucketBase, dis, N);
    aggXh1_k<<<nbuck, 256, 0, stream>>>(pairs, bucketBase, x, dis, W1, b1, h1, N);
    agg2b_k<<<nbuck, 256, 0, stream>>>(pairs, bucketBase, h1, dis, g, N);
    gemm64b_k<<<(N * HDIM + 255) / 256, 256, 0, stream>>>(g, W2, b2, h2, N);
    pq_k<<<(N * HDIM + 255) / 256, 256, 0, stream>>>(h2, Wm1, bm1, Ph, Qh, N);
    edgefin_k<<<2048, 256, 0, stream>>>(src, dst, ea, Ph, Qh, Wm1, Wm2, bm2, out, E);
}

// Round 9
// 676.118 us; speedup vs baseline: 2.6305x; 2.6305x over previous
//
#include <hip/hip_runtime.h>
#include <hip/hip_fp16.h>

// ---------------------------------------------------------------------------
// GNN policy: 2x GCNConv (N=100k, H=64) + per-edge MLP (132->64->1).
// R9 = R8 with the xs/xa workspace carve bug fixed (was N*4 BYTES, needs
// N*4 FLOATS; the overflow let aggX's xa writes corrupt live xs data ->
// absmax 2.9e-2). Bucket partition + per-bucket CSR-ify + register-gather
// aggregation with norms folded into node scaling (h1s = dis*h1).
// ---------------------------------------------------------------------------

#define HDIM 64
#define NBK 2048          // padded bucket count (nbuck = ceil(N/64) = 1563)

// ---------------- bucket partition ----------------

__global__ void __launch_bounds__(256) hist_k(const int* __restrict__ dst,
                                              int* __restrict__ bucketCnt,
                                              int E, int CH) {
    __shared__ int hist[NBK];
    int t = threadIdx.x;
    for (int b = t; b < NBK; b += 256) hist[b] = 0;
    __syncthreads();
    int rs = blockIdx.x * CH, re = min(E, rs + CH);
    for (int e = rs + t; e < re; e += 256) atomicAdd(&hist[dst[e] >> 6], 1);
    __syncthreads();
    for (int b = t; b < NBK; b += 256) {
        int h = hist[b];
        if (h) atomicAdd(&bucketCnt[b], h);
    }
}

// exclusive scan of 2048 bucket counts; writes base (2049) and cur (=base)
__global__ void bscan_k(const int* __restrict__ cnt, int* __restrict__ base,
                        int* __restrict__ cur, int E) {
    __shared__ int wtot[4];
    int t = threadIdx.x;
    int lane = t & 63, wid = t >> 6;
    int i0 = t * 8;
    int v[8]; int s = 0;
    #pragma unroll
    for (int j = 0; j < 8; j++) { v[j] = cnt[i0 + j]; s += v[j]; }
    int ws = s;
    #pragma unroll
    for (int d = 1; d < 64; d <<= 1) {
        int n = __shfl_up(ws, d, 64);
        if (lane >= d) ws += n;
    }
    if (lane == 63) wtot[wid] = ws;
    __syncthreads();
    int woff = 0;
    #pragma unroll
    for (int w = 0; w < 4; w++) if (w < wid) woff += wtot[w];
    int ex = woff + ws - s;
    #pragma unroll
    for (int j = 0; j < 8; j++) {
        base[i0 + j] = ex; cur[i0 + j] = ex;
        ex += v[j];
    }
    if (t == 255) base[NBK] = E;
}

// partition edges into bucket regions (LDS hist -> range reservation -> write)
__global__ void __launch_bounds__(256) part_k(const int* __restrict__ src,
                                              const int* __restrict__ dst,
                                              int* __restrict__ bucketCur,
                                              int2* __restrict__ pairs,
                                              int E, int CH) {
    __shared__ int hist[NBK];
    __shared__ int mybase[NBK];
    __shared__ int lcur[NBK];
    int t = threadIdx.x;
    int rs = blockIdx.x * CH, re = min(E, rs + CH);
    for (int b = t; b < NBK; b += 256) hist[b] = 0;
    __syncthreads();
    for (int e = rs + t; e < re; e += 256) atomicAdd(&hist[dst[e] >> 6], 1);
    __syncthreads();
    for (int b = t; b < NBK; b += 256) {
        int h = hist[b];
        mybase[b] = h ? atomicAdd(&bucketCur[b], h) : 0;
        lcur[b] = 0;
    }
    __syncthreads();
    for (int e = rs + t; e < re; e += 256) {
        int d = dst[e];
        int b = d >> 6;
        int o = atomicAdd(&lcur[b], 1);
        pairs[mybase[b] + o] = make_int2(src[e], d);
    }
}

// per-bucket: degree hist -> dis + rowptr (wave scan) -> scatter csrc
// (writes land in the bucket's contiguous window: no write amplification)
__global__ void __launch_bounds__(256) csrify_k(
    const int2* __restrict__ pairs, const int* __restrict__ base,
    int* __restrict__ csrc, int* __restrict__ rowptr,
    float* __restrict__ dis, int N, int E) {
    __shared__ int cnt[64];
    __shared__ int off[64];
    int b = blockIdx.x, t = threadIdx.x;
    if (t < 64) cnt[t] = 0;
    __syncthreads();
    int rs = base[b], re = base[b + 1];
    for (int i = rs + t; i < re; i += 256) atomicAdd(&cnt[pairs[i].y & 63], 1);
    __syncthreads();
    if (t < 64) {                       // lanes 0..63 of wave 0
        int deg = cnt[t];
        int n = b * 64 + t;
        if (n < N) dis[n] = rsqrtf((float)(deg + 1));
        int val = deg;
        #pragma unroll
        for (int d = 1; d < 64; d <<= 1) {
            int up = __shfl_up(val, d, 64);
            if (t >= d) val += up;
        }
        int excl = rs + val - deg;      // exclusive prefix within bucket
        off[t] = excl;
        if (n < N) rowptr[n] = excl;
    }
    if (b == 0 && t == 0) rowptr[N] = E;
    __syncthreads();
    for (int i = rs + t; i < re; i += 256) {
        int2 p = pairs[i];
        int o = atomicAdd(&off[p.y & 63], 1);
        csrc[o] = p.x;
    }
}

// ---------------- node scaling: xs = dis * x ----------------
__global__ void xs_k(const float* __restrict__ x, const float* __restrict__ dis,
                     float* __restrict__ xs, int N) {
    int i = blockIdx.x * 256 + threadIdx.x;
    if (i >= N) return;
    float d = dis[i];
    float4 v = *(const float4*)(x + (size_t)i * 4);
    v.x *= d; v.y *= d; v.z *= d; v.w *= d;
    *(float4*)(xs + (size_t)i * 4) = v;
}

// ---------------- layer 1 aggregation in x-space (4 threads/node) -----------
// xa[i] = dis_i * (sum_e xs[src_e] + xs[i])
__global__ void __launch_bounds__(256) aggX_k(
    const float* __restrict__ xs, float* __restrict__ xa,
    const int* __restrict__ rowptr, const int* __restrict__ csrc,
    const float* __restrict__ dis, int N) {
    int t = threadIdx.x;
    int node = blockIdx.x * 64 + (t >> 2);
    int f = t & 3;
    if (node >= N) return;
    int beg = rowptr[node], end = rowptr[node + 1];
    float acc = 0.f;
    int e = beg;
    for (; e + 2 <= end; e += 2) {
        int c0 = csrc[e], c1 = csrc[e + 1];
        float v0 = xs[(size_t)c0 * 4 + f];
        float v1 = xs[(size_t)c1 * 4 + f];
        acc += v0; acc += v1;
    }
    if (e < end) acc += xs[(size_t)csrc[e] * 4 + f];
    float di = dis[node];
    xa[(size_t)node * 4 + f] = di * (acc + xs[(size_t)node * 4 + f]);
}

// h1s = dis * relu(xa @ W1 + b1), stored fp16
__global__ void h1_k(const float* __restrict__ xa, const float* __restrict__ W1,
                     const float* __restrict__ b1, const float* __restrict__ dis,
                     __half* __restrict__ h1s, int N) {
    int gid = blockIdx.x * 256 + threadIdx.x;
    if (gid >= N * HDIM) return;
    int i = gid >> 6, f = gid & 63;
    float4 v = *(const float4*)(xa + (size_t)i * 4);
    float acc = b1[f];
    acc = fmaf(v.x, W1[f], acc);
    acc = fmaf(v.y, W1[64 + f], acc);
    acc = fmaf(v.z, W1[128 + f], acc);
    acc = fmaf(v.w, W1[192 + f], acc);
    h1s[gid] = __float2half(dis[i] * fmaxf(acc, 0.f));
}

// ---------------- layer 2 aggregation (wave/node, register accum) -----------
// g[i] = dis_i * (sum_e h1s[src_e] + h1s[i])   (fp32 accum, fp16 out)
__global__ void __launch_bounds__(256) agg2_k(
    const __half* __restrict__ h1s, __half* __restrict__ g,
    const int* __restrict__ rowptr, const int* __restrict__ csrc,
    const float* __restrict__ dis, int N) {
    int wid = threadIdx.x >> 6, lane = threadIdx.x & 63;
    int i = blockIdx.x * 4 + wid;
    if (i >= N) return;
    int beg = rowptr[i], end = rowptr[i + 1];
    int side = lane >> 5, lh = lane & 31;   // lanes 0-31: edge e; 32-63: e+1
    float ax = 0.f, ay = 0.f;
    int e = beg;
    for (; e + 4 <= end; e += 4) {          // 2 edges/side x 2 unroll
        int c0 = csrc[e + side];
        int c1 = csrc[e + 2 + side];
        float2 f0 = __half22float2(*(const __half2*)(h1s + (size_t)c0 * HDIM + lh * 2));
        float2 f1 = __half22float2(*(const __half2*)(h1s + (size_t)c1 * HDIM + lh * 2));
        ax += f0.x + f1.x; ay += f0.y + f1.y;
    }
    if (e + 2 <= end) {
        int c = csrc[e + side];
        float2 f0 = __half22float2(*(const __half2*)(h1s + (size_t)c * HDIM + lh * 2));
        ax += f0.x; ay += f0.y;
        e += 2;
    }
    if (e < end && side == 0) {             // odd remainder: side 0 only
        int c = csrc[e];
        float2 f0 = __half22float2(*(const __half2*)(h1s + (size_t)c * HDIM + lh * 2));
        ax += f0.x; ay += f0.y;
    }
    ax += __shfl_xor(ax, 32, 64);
    ay += __shfl_xor(ay, 32, 64);
    if (side == 0) {
        float di = dis[i];
        float2 hf = __half22float2(*(const __half2*)(h1s + (size_t)i * HDIM + lh * 2));
        ax = di * (ax + hf.x);
        ay = di * (ay + hf.y);
        *(__half2*)(g + (size_t)i * HDIM + lh * 2) = __floats2half2_rn(ax, ay);
    }
}

// ---------------- h2 = relu(g @ W2 + b2) ----------------
__global__ void gemm64b_k(const __half* __restrict__ gin, const float* __restrict__ W2,
                          const float* __restrict__ b2, float* __restrict__ h2, int N) {
    __shared__ float w[64 * 64];
    int t = threadIdx.x;
    for (int j = t; j < 64 * 64; j += 256) w[j] = W2[j];
    __syncthreads();
    int gid = blockIdx.x * 256 + t;
    if (gid >= N * HDIM) return;
    int i = gid >> 6, f = gid & 63;
    const __half2* hr = (const __half2*)(gin + (size_t)i * HDIM);
    float acc = 0.f;
    #pragma unroll 8
    for (int k = 0; k < 32; k++) {
        float2 hv = __half22float2(hr[k]);
        acc = fmaf(hv.x, w[(2 * k) * 64 + f], acc);
        acc = fmaf(hv.y, w[(2 * k + 1) * 64 + f], acc);
    }
    h2[gid] = fmaxf(acc + b2[f], 0.f);
}

// P = h2@Wm1[0:64]+bm1, Q = h2@Wm1[64:128]  (fp16)
__global__ void pq_k(const float* __restrict__ h, const float* __restrict__ Wm1,
                     const float* __restrict__ bm1,
                     __half* __restrict__ Ph, __half* __restrict__ Qh, int N) {
    __shared__ float w[128 * 64];
    int t = threadIdx.x;
    for (int j = t; j < 128 * 64; j += 256) w[j] = Wm1[j];
    __syncthreads();
    int gid = blockIdx.x * 256 + t;
    if (gid >= N * HDIM) return;
    int i = gid >> 6, f = gid & 63;
    const float* hr = h + (size_t)i * HDIM;
    float a = bm1[f], b = 0.f;
    #pragma unroll 8
    for (int k = 0; k < 64; k++) {
        float hv = hr[k];
        a = fmaf(hv, w[k * 64 + f], a);
        b = fmaf(hv, w[(64 + k) * 64 + f], b);
    }
    Ph[gid] = __float2half(a);
    Qh[gid] = __float2half(b);
}

// ---------------- edge finalize (verbatim R6) ----------------
__device__ __forceinline__ float mlp8(uint4 pv, uint4 qv, float4 eav,
                                      const float wer[4][8], const float w2r[8]) {
    float p = 0.f;
    #pragma unroll
    for (int w = 0; w < 4; w++) {
        unsigned pu = (&pv.x)[w], qu = (&qv.x)[w];
        float2 pf = __half22float2(__builtin_bit_cast(__half2, pu));
        float2 qf = __half22float2(__builtin_bit_cast(__half2, qu));
        int j0 = 2 * w, j1 = 2 * w + 1;
        float z0 = pf.x + qf.x;
        z0 = fmaf(eav.x, wer[0][j0], z0); z0 = fmaf(eav.y, wer[1][j0], z0);
        z0 = fmaf(eav.z, wer[2][j0], z0); z0 = fmaf(eav.w, wer[3][j0], z0);
        float z1 = pf.y + qf.y;
        z1 = fmaf(eav.x, wer[0][j1], z1); z1 = fmaf(eav.y, wer[1][j1], z1);
        z1 = fmaf(eav.z, wer[2][j1], z1); z1 = fmaf(eav.w, wer[3][j1], z1);
        p = fmaf(fmaxf(z0, 0.f), w2r[j0], p);
        p = fmaf(fmaxf(z1, 0.f), w2r[j1], p);
    }
    return p;
}

__global__ void __launch_bounds__(256) edgefin_k(
    const int* __restrict__ src, const int* __restrict__ dst,
    const float* __restrict__ ea,
    const __half* __restrict__ Ph, const __half* __restrict__ Qh,
    const float* __restrict__ Wm1, const float* __restrict__ Wm2,
    const float* __restrict__ bm2, float* __restrict__ out, int E) {
    int q = threadIdx.x & 7;
    int fb = q * 8;
    float w2r[8];
    float wer[4][8];
    *(float4*)&w2r[0] = *(const float4*)(Wm2 + fb);
    *(float4*)&w2r[4] = *(const float4*)(Wm2 + fb + 4);
    #pragma unroll
    for (int r = 0; r < 4; r++) {
        *(float4*)&wer[r][0] = *(const float4*)(Wm1 + (128 + r) * 64 + fb);
        *(float4*)&wer[r][4] = *(const float4*)(Wm1 + (128 + r) * 64 + fb + 4);
    }
    float b2v = bm2[0];

    int base = blockIdx.x * 64 + (threadIdx.x >> 3);
    int gstride = gridDim.x * 64;
    for (int e1 = base; e1 < E; e1 += gstride) {
        int e2 = e1 + 32; int e2c = (e2 < E) ? e2 : (E - 1);
        int s1 = src[e1], d1 = dst[e1];
        int s2 = src[e2c], d2 = dst[e2c];
        uint4 pv1 = *(const uint4*)((const unsigned short*)Ph + (size_t)s1 * HDIM + fb);
        uint4 qv1 = *(const uint4*)((const unsigned short*)Qh + (size_t)d1 * HDIM + fb);
        uint4 pv2 = *(const uint4*)((const unsigned short*)Ph + (size_t)s2 * HDIM + fb);
        uint4 qv2 = *(const uint4*)((const unsigned short*)Qh + (size_t)d2 * HDIM + fb);
        float4 ea1 = *(const float4*)(ea + (size_t)e1 * 4);
        float4 ea2 = *(const float4*)(ea + (size_t)e2c * 4);
        float p1 = mlp8(pv1, qv1, ea1, wer, w2r);
        float p2 = mlp8(pv2, qv2, ea2, wer, w2r);
        p1 += __shfl_xor(p1, 1, 64); p1 += __shfl_xor(p1, 2, 64); p1 += __shfl_xor(p1, 4, 64);
        p2 += __shfl_xor(p2, 1, 64); p2 += __shfl_xor(p2, 2, 64); p2 += __shfl_xor(p2, 4, 64);
        if (q == 0) {
            out[e1] = p1 + b2v;
            if (e2 < E) out[e2] = p2 + b2v;
        }
    }
}

extern "C" void kernel_launch(void* const* d_in, const int* in_sizes, int n_in,
                              void* d_out, int out_size, void* d_ws, size_t ws_size,
                              hipStream_t stream) {
    const float* x   = (const float*)d_in[0];
    const int*   ei  = (const int*)d_in[1];
    const float* ea  = (const float*)d_in[2];
    const float* W1  = (const float*)d_in[3];
    const float* b1  = (const float*)d_in[4];
    const float* W2  = (const float*)d_in[5];
    const float* b2  = (const float*)d_in[6];
    const float* Wm1 = (const float*)d_in[7];
    const float* bm1 = (const float*)d_in[8];
    const float* Wm2 = (const float*)d_in[9];
    const float* bm2 = (const float*)d_in[10];
    float* out = (float*)d_out;

    int N = in_sizes[0] / 4;    // 100000
    int E = in_sizes[1] / 2;    // 3200000
    const int* src = ei;
    const int* dst = ei + E;
    int nbuck = (N + 63) >> 6;  // 1563

    char* wp = (char*)d_ws;
    auto carve = [&](size_t bytes) -> void* {
        void* p = (void*)wp;
        wp += (bytes + 255) & ~(size_t)255;
        return p;
    };
    int*   bucketCnt  = (int*)carve(NBK * 4);
    int*   bucketBase = (int*)carve((NBK + 1) * 4);
    int*   bucketCur  = (int*)carve(NBK * 4);
    float* dis        = (float*)carve((size_t)N * 4);
    int*   rowptr     = (int*)carve((size_t)(N + 1) * 4);
    int*   csrc       = (int*)carve((size_t)E * 4);
    int2*  pairs      = (int2*)carve((size_t)E * 8);    // dead after csrify -> h2
    float* xs         = (float*)carve((size_t)N * 4 * sizeof(float));  // N x 4 FLOATS (R8 bug: was N*4 bytes)
    float* xa         = (float*)carve((size_t)N * 4 * sizeof(float));  // N x 4 FLOATS
    __half* S2        = (__half*)carve((size_t)N * HDIM * 2);   // h1s -> Qh
    __half* S3        = (__half*)carve((size_t)N * HDIM * 2);   // g   -> Ph
    float*  h2 = (float*)pairs;   // overlay: pairs dead after csrify_k
    __half* h1s = S2;
    __half* g   = S3;
    __half* Ph  = S3;
    __half* Qh  = S2;

    hipMemsetAsync(bucketCnt, 0, NBK * 4, stream);

    int CH = (E + 511) / 512;   // ~6251 edges per partition block

    hist_k<<<512, 256, 0, stream>>>(dst, bucketCnt, E, CH);
    bscan_k<<<1, 256, 0, stream>>>(bucketCnt, bucketBase, bucketCur, E);
    part_k<<<512, 256, 0, stream>>>(src, dst, bucketCur, pairs, E, CH);
    csrify_k<<<nbuck, 256, 0, stream>>>(pairs, bucketBase, csrc, rowptr, dis, N, E);
    xs_k<<<(N + 255) / 256, 256, 0, stream>>>(x, dis, xs, N);
    aggX_k<<<(N + 63) / 64, 256, 0, stream>>>(xs, xa, rowptr, csrc, dis, N);
    h1_k<<<(N * HDIM + 255) / 256, 256, 0, stream>>>(xa, W1, b1, dis, h1s, N);
    agg2_k<<<(N + 3) / 4, 256, 0, stream>>>(h1s, g, rowptr, csrc, dis, N);
    gemm64b_k<<<(N * HDIM + 255) / 256, 256, 0, stream>>>(g, W2, b2, h2, N);
    pq_k<<<(N * HDIM + 255) / 256, 256, 0, stream>>>(h2, Wm1, bm1, Ph, Qh, N);
    edgefin_k<<<2048, 256, 0, stream>>>(src, dst, ea, Ph, Qh, Wm1, Wm2, bm2, out, E);
}

// Round 10
// 616.869 us; speedup vs baseline: 2.8832x; 1.0960x over previous
//
#include <hip/hip_runtime.h>
#include <hip/hip_fp16.h>

// ---------------------------------------------------------------------------
// GNN policy: 2x GCNConv (N=100k, H=64) + per-edge MLP (132->64->1).
// R10 = R9 + ILP/fusion: (1) edgefin 4 edges per 8-lane group (12 loads in
// flight, was 6); (2) agg2 4 rows x 16-lane x 8B loads, 8 gathers in flight
// (was 4); (3) gemm64b+pq fused (W2+Wm1 in 48KB LDS, h2 row in registers,
// __shfl broadcast) killing the 51MB h2 round-trip. Same algorithm/numerics.
// ---------------------------------------------------------------------------

#define HDIM 64
#define NBK 2048          // padded bucket count (nbuck = ceil(N/64) = 1563)

// ---------------- bucket partition ----------------

__global__ void __launch_bounds__(256) hist_k(const int* __restrict__ dst,
                                              int* __restrict__ bucketCnt,
                                              int E, int CH) {
    __shared__ int hist[NBK];
    int t = threadIdx.x;
    for (int b = t; b < NBK; b += 256) hist[b] = 0;
    __syncthreads();
    int rs = blockIdx.x * CH, re = min(E, rs + CH);
    for (int e = rs + t; e < re; e += 256) atomicAdd(&hist[dst[e] >> 6], 1);
    __syncthreads();
    for (int b = t; b < NBK; b += 256) {
        int h = hist[b];
        if (h) atomicAdd(&bucketCnt[b], h);
    }
}

// exclusive scan of 2048 bucket counts; writes base (2049) and cur (=base)
__global__ void bscan_k(const int* __restrict__ cnt, int* __restrict__ base,
                        int* __restrict__ cur, int E) {
    __shared__ int wtot[4];
    int t = threadIdx.x;
    int lane = t & 63, wid = t >> 6;
    int i0 = t * 8;
    int v[8]; int s = 0;
    #pragma unroll
    for (int j = 0; j < 8; j++) { v[j] = cnt[i0 + j]; s += v[j]; }
    int ws = s;
    #pragma unroll
    for (int d = 1; d < 64; d <<= 1) {
        int n = __shfl_up(ws, d, 64);
        if (lane >= d) ws += n;
    }
    if (lane == 63) wtot[wid] = ws;
    __syncthreads();
    int woff = 0;
    #pragma unroll
    for (int w = 0; w < 4; w++) if (w < wid) woff += wtot[w];
    int ex = woff + ws - s;
    #pragma unroll
    for (int j = 0; j < 8; j++) {
        base[i0 + j] = ex; cur[i0 + j] = ex;
        ex += v[j];
    }
    if (t == 255) base[NBK] = E;
}

// partition edges into bucket regions (LDS hist -> range reservation -> write)
__global__ void __launch_bounds__(256) part_k(const int* __restrict__ src,
                                              const int* __restrict__ dst,
                                              int* __restrict__ bucketCur,
                                              int2* __restrict__ pairs,
                                              int E, int CH) {
    __shared__ int hist[NBK];
    __shared__ int mybase[NBK];
    __shared__ int lcur[NBK];
    int t = threadIdx.x;
    int rs = blockIdx.x * CH, re = min(E, rs + CH);
    for (int b = t; b < NBK; b += 256) hist[b] = 0;
    __syncthreads();
    for (int e = rs + t; e < re; e += 256) atomicAdd(&hist[dst[e] >> 6], 1);
    __syncthreads();
    for (int b = t; b < NBK; b += 256) {
        int h = hist[b];
        mybase[b] = h ? atomicAdd(&bucketCur[b], h) : 0;
        lcur[b] = 0;
    }
    __syncthreads();
    for (int e = rs + t; e < re; e += 256) {
        int d = dst[e];
        int b = d >> 6;
        int o = atomicAdd(&lcur[b], 1);
        pairs[mybase[b] + o] = make_int2(src[e], d);
    }
}

// per-bucket: degree hist -> dis + rowptr (wave scan) -> scatter csrc
__global__ void __launch_bounds__(256) csrify_k(
    const int2* __restrict__ pairs, const int* __restrict__ base,
    int* __restrict__ csrc, int* __restrict__ rowptr,
    float* __restrict__ dis, int N, int E) {
    __shared__ int cnt[64];
    __shared__ int off[64];
    int b = blockIdx.x, t = threadIdx.x;
    if (t < 64) cnt[t] = 0;
    __syncthreads();
    int rs = base[b], re = base[b + 1];
    for (int i = rs + t; i < re; i += 256) atomicAdd(&cnt[pairs[i].y & 63], 1);
    __syncthreads();
    if (t < 64) {                       // lanes 0..63 of wave 0
        int deg = cnt[t];
        int n = b * 64 + t;
        if (n < N) dis[n] = rsqrtf((float)(deg + 1));
        int val = deg;
        #pragma unroll
        for (int d = 1; d < 64; d <<= 1) {
            int up = __shfl_up(val, d, 64);
            if (t >= d) val += up;
        }
        int excl = rs + val - deg;      // exclusive prefix within bucket
        off[t] = excl;
        if (n < N) rowptr[n] = excl;
    }
    if (b == 0 && t == 0) rowptr[N] = E;
    __syncthreads();
    for (int i = rs + t; i < re; i += 256) {
        int2 p = pairs[i];
        int o = atomicAdd(&off[p.y & 63], 1);
        csrc[o] = p.x;
    }
}

// ---------------- node scaling: xs = dis * x ----------------
__global__ void xs_k(const float* __restrict__ x, const float* __restrict__ dis,
                     float* __restrict__ xs, int N) {
    int i = blockIdx.x * 256 + threadIdx.x;
    if (i >= N) return;
    float d = dis[i];
    float4 v = *(const float4*)(x + (size_t)i * 4);
    v.x *= d; v.y *= d; v.z *= d; v.w *= d;
    *(float4*)(xs + (size_t)i * 4) = v;
}

// ---------------- layer 1 aggregation in x-space (4 threads/node) -----------
__global__ void __launch_bounds__(256) aggX_k(
    const float* __restrict__ xs, float* __restrict__ xa,
    const int* __restrict__ rowptr, const int* __restrict__ csrc,
    const float* __restrict__ dis, int N) {
    int t = threadIdx.x;
    int node = blockIdx.x * 64 + (t >> 2);
    int f = t & 3;
    if (node >= N) return;
    int beg = rowptr[node], end = rowptr[node + 1];
    float acc = 0.f;
    int e = beg;
    for (; e + 2 <= end; e += 2) {
        int c0 = csrc[e], c1 = csrc[e + 1];
        float v0 = xs[(size_t)c0 * 4 + f];
        float v1 = xs[(size_t)c1 * 4 + f];
        acc += v0; acc += v1;
    }
    if (e < end) acc += xs[(size_t)csrc[e] * 4 + f];
    float di = dis[node];
    xa[(size_t)node * 4 + f] = di * (acc + xs[(size_t)node * 4 + f]);
}

// h1s = dis * relu(xa @ W1 + b1), stored fp16
__global__ void h1_k(const float* __restrict__ xa, const float* __restrict__ W1,
                     const float* __restrict__ b1, const float* __restrict__ dis,
                     __half* __restrict__ h1s, int N) {
    int gid = blockIdx.x * 256 + threadIdx.x;
    if (gid >= N * HDIM) return;
    int i = gid >> 6, f = gid & 63;
    float4 v = *(const float4*)(xa + (size_t)i * 4);
    float acc = b1[f];
    acc = fmaf(v.x, W1[f], acc);
    acc = fmaf(v.y, W1[64 + f], acc);
    acc = fmaf(v.z, W1[128 + f], acc);
    acc = fmaf(v.w, W1[192 + f], acc);
    h1s[gid] = __float2half(dis[i] * fmaxf(acc, 0.f));
}

// ---------------- layer 2 aggregation: 4 rows x 16 lanes x 8B, 2-unroll -----
// g[i] = dis_i * (sum_e h1s[src_e] + h1s[i])   (fp32 accum, fp16 out)
__device__ __forceinline__ void acc4(const __half* __restrict__ p,
                                     float& a0, float& a1, float& a2, float& a3) {
    uint2 u = *(const uint2*)p;
    float2 f01 = __half22float2(__builtin_bit_cast(__half2, u.x));
    float2 f23 = __half22float2(__builtin_bit_cast(__half2, u.y));
    a0 += f01.x; a1 += f01.y; a2 += f23.x; a3 += f23.y;
}

__global__ void __launch_bounds__(256) agg2_k(
    const __half* __restrict__ h1s, __half* __restrict__ g,
    const int* __restrict__ rowptr, const int* __restrict__ csrc,
    const float* __restrict__ dis, int N) {
    int wid = threadIdx.x >> 6, lane = threadIdx.x & 63;
    int i = blockIdx.x * 4 + wid;
    if (i >= N) return;
    int beg = rowptr[i], end = rowptr[i + 1];
    int rid = lane >> 4, lh = lane & 15;    // row-slot 0..3, features lh*4..+3
    float a0 = 0.f, a1 = 0.f, a2 = 0.f, a3 = 0.f;
    int e = beg;
    for (; e + 8 <= end; e += 8) {          // 8 row-gathers in flight per wave
        int c0 = csrc[e + rid];
        int c1 = csrc[e + 4 + rid];
        acc4(h1s + (size_t)c0 * HDIM + lh * 4, a0, a1, a2, a3);
        acc4(h1s + (size_t)c1 * HDIM + lh * 4, a0, a1, a2, a3);
    }
    if (e + 4 <= end) {
        int c = csrc[e + rid];
        acc4(h1s + (size_t)c * HDIM + lh * 4, a0, a1, a2, a3);
        e += 4;
    }
    int rem = end - e;                      // 0..3
    if (rid < rem) {
        int c = csrc[e + rid];
        acc4(h1s + (size_t)c * HDIM + lh * 4, a0, a1, a2, a3);
    }
    a0 += __shfl_xor(a0, 16, 64); a0 += __shfl_xor(a0, 32, 64);
    a1 += __shfl_xor(a1, 16, 64); a1 += __shfl_xor(a1, 32, 64);
    a2 += __shfl_xor(a2, 16, 64); a2 += __shfl_xor(a2, 32, 64);
    a3 += __shfl_xor(a3, 16, 64); a3 += __shfl_xor(a3, 32, 64);
    if (rid == 0) {
        float di = dis[i];
        uint2 u = *(const uint2*)(h1s + (size_t)i * HDIM + lh * 4);
        float2 s01 = __half22float2(__builtin_bit_cast(__half2, u.x));
        float2 s23 = __half22float2(__builtin_bit_cast(__half2, u.y));
        a0 = di * (a0 + s01.x); a1 = di * (a1 + s01.y);
        a2 = di * (a2 + s23.x); a3 = di * (a3 + s23.y);
        uint2 o;
        o.x = __builtin_bit_cast(unsigned, __floats2half2_rn(a0, a1));
        o.y = __builtin_bit_cast(unsigned, __floats2half2_rn(a2, a3));
        *(uint2*)(g + (size_t)i * HDIM + lh * 4) = o;
    }
}

// ---------------- fused: h2 = relu(g@W2+b2); P,Q = h2@Wm1 (+bm1) ------------
// wave = node, lane = feature; h2 row lives in registers, __shfl broadcast.
__global__ void __launch_bounds__(256) pqfuse_k(
    const __half* __restrict__ g, const float* __restrict__ W2,
    const float* __restrict__ b2, const float* __restrict__ Wm1,
    const float* __restrict__ bm1,
    __half* __restrict__ Ph, __half* __restrict__ Qh, int N) {
    __shared__ float w2[64 * 64];    // 16 KB
    __shared__ float wm[128 * 64];   // 32 KB
    int t = threadIdx.x;
    for (int j = t; j < 64 * 64; j += 256) w2[j] = W2[j];
    for (int j = t; j < 128 * 64; j += 256) wm[j] = Wm1[j];
    __syncthreads();
    int wave = t >> 6, f = t & 63;
    float b2v = b2[f], bm1v = bm1[f];
    for (int i = blockIdx.x * 4 + wave; i < N; i += gridDim.x * 4) {
        const __half2* hr = (const __half2*)(g + (size_t)i * HDIM);
        float acc = 0.f;
        #pragma unroll 8
        for (int k = 0; k < 32; k++) {
            float2 hv = __half22float2(hr[k]);   // wave-uniform broadcast load
            acc = fmaf(hv.x, w2[(2 * k) * 64 + f], acc);
            acc = fmaf(hv.y, w2[(2 * k + 1) * 64 + f], acc);
        }
        float h2v = fmaxf(acc + b2v, 0.f);       // lane f holds h2[i][f]
        float a = bm1v, b = 0.f;
        #pragma unroll 8
        for (int k = 0; k < 64; k++) {
            float hk = __shfl(h2v, k, 64);       // broadcast h2[i][k]
            a = fmaf(hk, wm[k * 64 + f], a);
            b = fmaf(hk, wm[(64 + k) * 64 + f], b);
        }
        Ph[(size_t)i * HDIM + f] = __float2half(a);
        Qh[(size_t)i * HDIM + f] = __float2half(b);
    }
}

// ---------------- edge finalize: 4 edges per 8-lane group ----------------
__device__ __forceinline__ float mlp8(uint4 pv, uint4 qv, float4 eav,
                                      const float wer[4][8], const float w2r[8]) {
    float p = 0.f;
    #pragma unroll
    for (int w = 0; w < 4; w++) {
        unsigned pu = (&pv.x)[w], qu = (&qv.x)[w];
        float2 pf = __half22float2(__builtin_bit_cast(__half2, pu));
        float2 qf = __half22float2(__builtin_bit_cast(__half2, qu));
        int j0 = 2 * w, j1 = 2 * w + 1;
        float z0 = pf.x + qf.x;
        z0 = fmaf(eav.x, wer[0][j0], z0); z0 = fmaf(eav.y, wer[1][j0], z0);
        z0 = fmaf(eav.z, wer[2][j0], z0); z0 = fmaf(eav.w, wer[3][j0], z0);
        float z1 = pf.y + qf.y;
        z1 = fmaf(eav.x, wer[0][j1], z1); z1 = fmaf(eav.y, wer[1][j1], z1);
        z1 = fmaf(eav.z, wer[2][j1], z1); z1 = fmaf(eav.w, wer[3][j1], z1);
        p = fmaf(fmaxf(z0, 0.f), w2r[j0], p);
        p = fmaf(fmaxf(z1, 0.f), w2r[j1], p);
    }
    return p;
}

__global__ void __launch_bounds__(256) edgefin_k(
    const int* __restrict__ src, const int* __restrict__ dst,
    const float* __restrict__ ea,
    const __half* __restrict__ Ph, const __half* __restrict__ Qh,
    const float* __restrict__ Wm1, const float* __restrict__ Wm2,
    const float* __restrict__ bm2, float* __restrict__ out, int E) {
    int q = threadIdx.x & 7;
    int fb = q * 8;
    float w2r[8];
    float wer[4][8];
    *(float4*)&w2r[0] = *(const float4*)(Wm2 + fb);
    *(float4*)&w2r[4] = *(const float4*)(Wm2 + fb + 4);
    #pragma unroll
    for (int r = 0; r < 4; r++) {
        *(float4*)&wer[r][0] = *(const float4*)(Wm1 + (128 + r) * 64 + fb);
        *(float4*)&wer[r][4] = *(const float4*)(Wm1 + (128 + r) * 64 + fb + 4);
    }
    float b2v = bm2[0];

    int base = blockIdx.x * 128 + (threadIdx.x >> 3);  // 128 edges per pass
    int gstride = gridDim.x * 128;
    for (int e1 = base; e1 < E; e1 += gstride) {
        int ec[4];
        uint4 pv[4], qv[4];
        float4 eav[4];
        #pragma unroll
        for (int j = 0; j < 4; j++) {
            int e = e1 + j * 32;
            ec[j] = (e < E) ? e : (E - 1);
        }
        #pragma unroll
        for (int j = 0; j < 4; j++) {
            int s = src[ec[j]], d = dst[ec[j]];
            pv[j] = *(const uint4*)((const unsigned short*)Ph + (size_t)s * HDIM + fb);
            qv[j] = *(const uint4*)((const unsigned short*)Qh + (size_t)d * HDIM + fb);
            eav[j] = *(const float4*)(ea + (size_t)ec[j] * 4);
        }
        float p[4];
        #pragma unroll
        for (int j = 0; j < 4; j++) p[j] = mlp8(pv[j], qv[j], eav[j], wer, w2r);
        #pragma unroll
        for (int j = 0; j < 4; j++) {
            p[j] += __shfl_xor(p[j], 1, 64);
            p[j] += __shfl_xor(p[j], 2, 64);
            p[j] += __shfl_xor(p[j], 4, 64);
        }
        if (q == 0) {
            #pragma unroll
            for (int j = 0; j < 4; j++) {
                int e = e1 + j * 32;
                if (e < E) out[e] = p[j] + b2v;
            }
        }
    }
}

extern "C" void kernel_launch(void* const* d_in, const int* in_sizes, int n_in,
                              void* d_out, int out_size, void* d_ws, size_t ws_size,
                              hipStream_t stream) {
    const float* x   = (const float*)d_in[0];
    const int*   ei  = (const int*)d_in[1];
    const float* ea  = (const float*)d_in[2];
    const float* W1  = (const float*)d_in[3];
    const float* b1  = (const float*)d_in[4];
    const float* W2  = (const float*)d_in[5];
    const float* b2  = (const float*)d_in[6];
    const float* Wm1 = (const float*)d_in[7];
    const float* bm1 = (const float*)d_in[8];
    const float* Wm2 = (const float*)d_in[9];
    const float* bm2 = (const float*)d_in[10];
    float* out = (float*)d_out;

    int N = in_sizes[0] / 4;    // 100000
    int E = in_sizes[1] / 2;    // 3200000
    const int* src = ei;
    const int* dst = ei + E;
    int nbuck = (N + 63) >> 6;  // 1563

    char* wp = (char*)d_ws;
    auto carve = [&](size_t bytes) -> void* {
        void* p = (void*)wp;
        wp += (bytes + 255) & ~(size_t)255;
        return p;
    };
    int*   bucketCnt  = (int*)carve(NBK * 4);
    int*   bucketBase = (int*)carve((NBK + 1) * 4);
    int*   bucketCur  = (int*)carve(NBK * 4);
    float* dis        = (float*)carve((size_t)N * 4);
    int*   rowptr     = (int*)carve((size_t)(N + 1) * 4);
    int*   csrc       = (int*)carve((size_t)E * 4);
    int2*  pairs      = (int2*)carve((size_t)E * 8);    // dead after csrify -> Ph
    float* xs         = (float*)carve((size_t)N * 4 * sizeof(float));
    float* xa         = (float*)carve((size_t)N * 4 * sizeof(float));
    __half* S2        = (__half*)carve((size_t)N * HDIM * 2);   // h1s -> Qh
    __half* S3        = (__half*)carve((size_t)N * HDIM * 2);   // g
    __half* h1s = S2;
    __half* g   = S3;
    __half* Ph  = (__half*)pairs;   // pairs dead after csrify_k
    __half* Qh  = S2;               // h1s dead after agg2_k

    hipMemsetAsync(bucketCnt, 0, NBK * 4, stream);

    int CH = (E + 511) / 512;   // ~6251 edges per partition block

    hist_k<<<512, 256, 0, stream>>>(dst, bucketCnt, E, CH);
    bscan_k<<<1, 256, 0, stream>>>(bucketCnt, bucketBase, bucketCur, E);
    part_k<<<512, 256, 0, stream>>>(src, dst, bucketCur, pairs, E, CH);
    csrify_k<<<nbuck, 256, 0, stream>>>(pairs, bucketBase, csrc, rowptr, dis, N, E);
    xs_k<<<(N + 255) / 256, 256, 0, stream>>>(x, dis, xs, N);
    aggX_k<<<(N + 63) / 64, 256, 0, stream>>>(xs, xa, rowptr, csrc, dis, N);
    h1_k<<<(N * HDIM + 255) / 256, 256, 0, stream>>>(xa, W1, b1, dis, h1s, N);
    agg2_k<<<(N + 3) / 4, 256, 0, stream>>>(h1s, g, rowptr, csrc, dis, N);
    pqfuse_k<<<512, 256, 0, stream>>>(g, W2, b2, Wm1, bm1, Ph, Qh, N);
    edgefin_k<<<2048, 256, 0, stream>>>(src, dst, ea, Ph, Qh, Wm1, Wm2, bm2, out, E);
}